// Round 8
// baseline (646.080 us; speedup 1.0000x reference)
//
#include <hip/hip_runtime.h>

typedef _Float16 f16;
typedef f16 f16x8 __attribute__((ext_vector_type(8)));
typedef float f32x4 __attribute__((ext_vector_type(4)));
typedef float f32x2 __attribute__((ext_vector_type(2)));
typedef unsigned u32;

#define MFMA16(a, b, c) __builtin_amdgcn_mfma_f32_16x16x32_f16(a, b, c, 0, 0, 0)

// packed-weight offsets in f16 elements within d_ws (16x16x32 frag layout)
// R weights are contiguous [0,46080) = 90KB; Q W2|W3 contiguous [87040,122880) = 70KB.
#define OFF_RW1A 0
#define OFF_RW2  10240
#define OFF_RW3  35840
#define OFF_QW1  46080
#define OFF_QW2  87040
#define OFF_QW3  112640
#define OFF_PW1  122880
#define OFF_PW2  163840
#define OFF_PW3  189440
#define PACK_BYTES 399360   // 199680 f16

// prep grid: [0,256) red0 partials | [256,355) pack | [355,363) qmax
//            [363,371) e1q | [371,627) c1/d1 | [627,1651) red1
#define PREP_BLOCKS 1651

struct InPtrs { const float* p[21]; };

__device__ const int g_mSrc[9] = {15, 17, 19, 9, 11, 13, 3, 5, 7};
__device__ const int g_mK0[9]  = {0, 0, 0, 128, 0, 0, 0, 0, 0};
__device__ const int g_mK[9]   = {64, 132, 132, 256, 132, 132, 256, 132, 132};
__device__ const int g_mN[9]   = {132, 132, 64, 132, 132, 64, 132, 132, 64};
__device__ const int g_mNT[9]  = {10, 10, 4, 10, 10, 4, 10, 10, 4};
__device__ const int g_mDst[9] = {OFF_RW1A, OFF_RW2, OFF_RW3, OFF_QW1, OFF_QW2, OFF_QW3,
                                  OFF_PW1, OFF_PW2, OFF_PW3};
__device__ const int g_mBlk0[9] = {256, 261, 274, 279, 299, 312, 317, 337, 350};

__global__ __launch_bounds__(256) void prep_kernel(InPtrs in, f16* __restrict__ wpk,
    float* __restrict__ c1, float* __restrict__ d1, float* __restrict__ e1q,
    float* __restrict__ qmax, float* __restrict__ red0p, float* __restrict__ red1)
{
  __shared__ float sbuf[1024];
  const int mb = blockIdx.x, t = threadIdx.x;

  if (mb < 256) {
    // red0 partial: max over 64 i's; block = (b, j-oct, i-half). Contiguous 2KB/i.
    const int b = mb >> 5, jo = (mb >> 1) & 15, ih = mb & 1;
    const float* base = in.p[2] + (size_t)b * 1048576 + (size_t)ih * 64 * 8192
                        + (size_t)jo * 512 + t * 2;
    f32x2 m[8];
    #pragma unroll
    for (int u = 0; u < 8; ++u) { m[u][0] = -3.4e38f; m[u][1] = -3.4e38f; }
    for (int i = 0; i < 64; i += 8) {
      #pragma unroll
      for (int u = 0; u < 8; ++u) {
        f32x2 v = *(const f32x2*)(base + (size_t)(i + u) * 8192);
        m[u][0] = fmaxf(m[u][0], v[0]);
        m[u][1] = fmaxf(m[u][1], v[1]);
      }
    }
    #pragma unroll
    for (int s = 4; s > 0; s >>= 1)
      #pragma unroll
      for (int u = 0; u < 4; ++u)
        if (u < s) {
          m[u][0] = fmaxf(m[u][0], m[u + s][0]);
          m[u][1] = fmaxf(m[u][1], m[u + s][1]);
        }
    *(f32x2*)(red0p + (size_t)ih * 65536 +
              ((size_t)(b * 128 + jo * 8 + (t >> 5))) * 64 + ((t * 2) & 63)) = m[0];
  } else if (mb < 355) {
    // weight pack into 16x16x32 MFMA fragment layout
    int mi = 8;
    while (mi > 0 && mb < g_mBlk0[mi]) --mi;
    const int NT = g_mNT[mi], K = g_mK[mi], N = g_mN[mi], K0 = g_mK0[mi];
    const int L = (mb - g_mBlk0[mi]) * 256 + t;
    const int lanes = ((K + 31) >> 5) * NT * 64;
    if (L < lanes) {
      const int lane = L & 63, tile = L >> 6;
      const int kk = tile / NT, nn = tile % NT;
      const float* src = in.p[g_mSrc[mi]];
      const int n = nn * 16 + (lane & 15);
      const int kb = kk * 32 + ((lane >> 4) << 3);
      f16x8 v;
      #pragma unroll
      for (int u = 0; u < 8; ++u) {
        const int k = kb + u;
        float f = (k < K && n < N) ? src[(size_t)(K0 + k) * N + n] : 0.f;
        v[u] = (f16)f;
      }
      *(f16x8*)(wpk + g_mDst[mi] + (size_t)L * 8) = v;
    }
  } else if (mb < 363) {
    // qmax[b,d] = max_i Q[b,i,d]
    const int b = mb - 355;
    const float* Qb = in.p[1] + (size_t)b * 128 * 128;
    const int d = t & 127, g = t >> 7;
    float m0 = -3.4e38f, m1 = m0, m2 = m0, m3 = m0;
    #pragma unroll
    for (int v = 0; v < 16; ++v) {
      const int i = g * 64 + v * 4;
      m0 = fmaxf(m0, Qb[(size_t)(i + 0) * 128 + d]);
      m1 = fmaxf(m1, Qb[(size_t)(i + 1) * 128 + d]);
      m2 = fmaxf(m2, Qb[(size_t)(i + 2) * 128 + d]);
      m3 = fmaxf(m3, Qb[(size_t)(i + 3) * 128 + d]);
    }
    sbuf[g * 128 + d] = fmaxf(fmaxf(m0, m1), fmaxf(m2, m3));
    __syncthreads();
    if (t < 128) qmax[b * 128 + t] = fmaxf(sbuf[t], sbuf[128 + t]);
  } else if (mb < 371) {
    // e1q[b,n] = P[b] . q_w1[0:128] + q_b1
    const int b = mb - 363;
    const float* P = in.p[0]; const float* qw1 = in.p[9]; const float* qb1 = in.p[10];
    if (t < 160) {
      float a = 0.f;
      if (t < 132) {
        float a0 = 0.f, a1 = 0.f, a2 = 0.f, a3 = 0.f;
        for (int k = 0; k < 128; k += 4) {
          a0 += P[b * 128 + k + 0] * qw1[(size_t)(k + 0) * 132 + t];
          a1 += P[b * 128 + k + 1] * qw1[(size_t)(k + 1) * 132 + t];
          a2 += P[b * 128 + k + 2] * qw1[(size_t)(k + 2) * 132 + t];
          a3 += P[b * 128 + k + 3] * qw1[(size_t)(k + 3) * 132 + t];
        }
        a = qb1[t] + (a0 + a1) + (a2 + a3);
      }
      e1q[b * 160 + t] = a;
    }
  } else if (mb < 627) {
    // c1/d1 (r-branch folded Q contributions), 4 Q-rows per block
    const int blk = mb - 371;
    const float* Q = in.p[1]; const float* rw1 = in.p[15]; const float* rb1 = in.p[16];
    for (int o = t; o < 512; o += 256) sbuf[o] = Q[(size_t)blk * 512 + o];
    __syncthreads();
    if (t < 160) {
      float cc[4], dd[4];
      #pragma unroll
      for (int r = 0; r < 4; ++r) { cc[r] = 0.f; dd[r] = 0.f; }
      if (t < 132) {
        const float bb = rb1[t];
        #pragma unroll
        for (int r = 0; r < 4; ++r) cc[r] = bb;
        for (int k = 0; k < 128; ++k) {
          const float wc = rw1[(size_t)(192 + k) * 132 + t];
          const float wd = rw1[(size_t)(64 + k) * 132 + t];
          #pragma unroll
          for (int r = 0; r < 4; ++r) {
            cc[r] += sbuf[r * 128 + k] * wc;
            dd[r] += sbuf[r * 128 + k] * wd;
          }
        }
      }
      for (int r = 0; r < 4; ++r) {
        c1[(size_t)(blk * 4 + r) * 160 + t] = cc[r];
        d1[(size_t)(blk * 4 + r) * 160 + t] = dd[r];
      }
    }
  } else {
    // red1[b,i,d] = max_j R[b,i,j,d]; one block per (b,i); contiguous loads.
    const int bi = mb - 627;
    const int d2 = t & 31, jg = t >> 5;
    const float* base = in.p[2] + (size_t)bi * 8192 + (size_t)jg * 1024 + d2 * 2;
    f32x2 m[4];
    #pragma unroll
    for (int u = 0; u < 4; ++u) { m[u][0] = -3.4e38f; m[u][1] = -3.4e38f; }
    #pragma unroll
    for (int v = 0; v < 16; v += 4) {
      #pragma unroll
      for (int u = 0; u < 4; ++u) {
        f32x2 vv = *(const f32x2*)(base + (size_t)(v + u) * 64);
        m[u][0] = fmaxf(m[u][0], vv[0]);
        m[u][1] = fmaxf(m[u][1], vv[1]);
      }
    }
    m[0][0] = fmaxf(fmaxf(m[0][0], m[1][0]), fmaxf(m[2][0], m[3][0]));
    m[0][1] = fmaxf(fmaxf(m[0][1], m[1][1]), fmaxf(m[2][1], m[3][1]));
    sbuf[jg * 64 + d2 * 2] = m[0][0];
    sbuf[jg * 64 + d2 * 2 + 1] = m[0][1];
    __syncthreads();
    if (t < 64) {
      float mm = sbuf[t];
      #pragma unroll
      for (int g2 = 1; g2 < 8; ++g2) mm = fmaxf(mm, sbuf[g2 * 64 + t]);
      red1[(size_t)bi * 64 + t] = mm;
    }
  }
}

__device__ __forceinline__ float sig5(float x) {
  return 1.f / (1.f + __expf(-5.f * x));
}

__device__ __forceinline__ u32 pk2(float a, float b) {
  typedef __fp16 fp16x2 __attribute__((ext_vector_type(2)));
  union { fp16x2 h; u32 u; } cv;
  cv.h = __builtin_amdgcn_cvt_pkrtz(a, b);
  return cv.u;
}

__device__ __forceinline__ f16x8 ld8(const float* p) {
  f32x4 v0 = *(const f32x4*)p, v1 = *(const f32x4*)(p + 4);
  union { u32 w[4]; f16x8 v; } U;
  U.w[0] = pk2(v0[0], v0[1]); U.w[1] = pk2(v0[2], v0[3]);
  U.w[2] = pk2(v1[0], v1[1]); U.w[3] = pk2(v1[2], v1[3]);
  return U.v;
}

__device__ __forceinline__ f16x8 ld8max(const float* p, int stride) {
  f32x4 a0 = *(const f32x4*)p, a1 = *(const f32x4*)(p + 4);
  f32x4 b0 = *(const f32x4*)(p + stride), b1 = *(const f32x4*)(p + stride + 4);
  union { u32 w[4]; f16x8 v; } U;
  U.w[0] = pk2(fmaxf(a0[0], b0[0]), fmaxf(a0[1], b0[1]));
  U.w[1] = pk2(fmaxf(a0[2], b0[2]), fmaxf(a0[3], b0[3]));
  U.w[2] = pk2(fmaxf(a1[0], b1[0]), fmaxf(a1[1], b1[1]));
  U.w[3] = pk2(fmaxf(a1[2], b1[2]), fmaxf(a1[3], b1[3]));
  return U.v;
}

// Layer-transition: build next-layer B-frag from two D-tiles entirely in regs.
// dest lane (g,i) word pair u/4: from lane ((2g + u/4)&3)*16 + i, tile 2c+(g>>1).
__device__ __forceinline__ f16x8 make_bfrag(const f32x4 ta, const f32x4 tb,
                                            int srcA, int srcB, bool glo) {
  u32 a0 = pk2(fmaxf(ta[0], 0.f), fmaxf(ta[1], 0.f));
  u32 a1 = pk2(fmaxf(ta[2], 0.f), fmaxf(ta[3], 0.f));
  u32 b0 = pk2(fmaxf(tb[0], 0.f), fmaxf(tb[1], 0.f));
  u32 b1 = pk2(fmaxf(tb[2], 0.f), fmaxf(tb[3], 0.f));
  u32 aA0 = (u32)__shfl((int)a0, srcA), aA1 = (u32)__shfl((int)a1, srcA);
  u32 bA0 = (u32)__shfl((int)b0, srcA), bA1 = (u32)__shfl((int)b1, srcA);
  u32 aB0 = (u32)__shfl((int)a0, srcB), aB1 = (u32)__shfl((int)a1, srcB);
  u32 bB0 = (u32)__shfl((int)b0, srcB), bB1 = (u32)__shfl((int)b1, srcB);
  union { u32 w[4]; f16x8 v; } U;
  U.w[0] = glo ? aA0 : bA0;
  U.w[1] = glo ? aA1 : bA1;
  U.w[2] = glo ? aB0 : bB0;
  U.w[3] = glo ? aB1 : bB1;
  return U.v;
}

// ---------------------------------------------------------------------------
// fused kernel: 256 blocks x 1024 threads (16 waves), 1 block/CU, 90KB LDS.
// Blocks [0,255): R branch — stage all R weights in LDS once, then each wave
//   grid-strides 16-row chunks (8192 total). Per-wave acc[10] (40 regs).
// Block 255: QP — stage QW2|QW3 (70KB); Q L1 weights + all P weights global.
// ---------------------------------------------------------------------------
__global__ __launch_bounds__(1024, 4) void fused_kernel(
    const float* __restrict__ R, const float* __restrict__ c1, const float* __restrict__ d1,
    const float* __restrict__ rb2, const float* __restrict__ rb3,
    const f16* __restrict__ wpk, float* __restrict__ outR,
    const float* __restrict__ P, const float* __restrict__ Q,
    const float* __restrict__ qb2, const float* __restrict__ qb3,
    const float* __restrict__ pb1, const float* __restrict__ pb2, const float* __restrict__ pb3,
    const float* __restrict__ e1q, const float* __restrict__ qmax,
    const float* __restrict__ red0p, const float* __restrict__ red1,
    float* __restrict__ outP, float* __restrict__ outQ)
{
  __shared__ f16 Wb[46080];   // 90 KB
  const int t = threadIdx.x, lane = t & 63, w = t >> 6;
  const int g = lane >> 4, i = lane & 15;
  const int nrow = g * 4;
  const bool glo = (g < 2);
  const int srcA = ((2 * g) & 3) * 16 + i;
  const int srcB = ((2 * g + 1) & 3) * 16 + i;
  const int bk = blockIdx.x;
  const bool isR = (bk < 255);

  {
    const f16* src = wpk + (isR ? 0 : OFF_QW2);
    const int total = isR ? 46080 : 35840;
    for (int idx = t * 8; idx < total; idx += 8192)
      *(f16x8*)(&Wb[idx]) = *(const f16x8*)(src + idx);
  }
  __syncthreads();

  if (isR) {
    const f16x8* W1p = (const f16x8*)(Wb);
    const f16x8* W2p = (const f16x8*)(Wb + 10240);
    const f16x8* W3p = (const f16x8*)(Wb + 35840);
    const int W = bk * 16 + w;          // wave id in [0,4080)
    #pragma unroll 1
    for (int chunk = W; chunk < 8192; chunk += 4080) {
      const int bi = chunk >> 3, rowbase = (chunk & 7) * 16;
      const int b = bi >> 7;
      // L1 acc init: c1[bi] + d1[b, row]
      const float* c1r = c1 + (size_t)bi * 160;
      const float* d1r = d1 + ((size_t)(b * 128 + rowbase + i)) * 160;
      f32x4 acc[10];
      #pragma unroll
      for (int tn = 0; tn < 10; ++tn)
        acc[tn] = *(const f32x4*)(c1r + tn * 16 + nrow)
                + *(const f32x4*)(d1r + tn * 16 + nrow);
      // L1: K=64 from R directly
      const float* Rb = R + (size_t)bi * 8192 + (size_t)(rowbase + i) * 64;
      #pragma unroll
      for (int c = 0; c < 2; ++c) {
        const f16x8 x = ld8(Rb + c * 32 + g * 8);
        #pragma unroll
        for (int tn = 0; tn < 10; ++tn)
          acc[tn] = MFMA16(W1p[(size_t)(c * 10 + tn) * 64 + lane], x, acc[tn]);
      }
      // transition 1
      f16x8 hf[5];
      #pragma unroll
      for (int c5 = 0; c5 < 5; ++c5)
        hf[c5] = make_bfrag(acc[2 * c5], acc[2 * c5 + 1], srcA, srcB, glo);
      // L2
      #pragma unroll
      for (int tn = 0; tn < 10; ++tn) {
        const int nb = tn * 16 + nrow;
        f32x4 bv = {0.f, 0.f, 0.f, 0.f};
        if (nb < 132) bv = *(const f32x4*)(rb2 + nb);
        acc[tn] = bv;
      }
      #pragma unroll
      for (int c5 = 0; c5 < 5; ++c5)
        #pragma unroll
        for (int tn = 0; tn < 10; ++tn)
          acc[tn] = MFMA16(W2p[(size_t)(c5 * 10 + tn) * 64 + lane], hf[c5], acc[tn]);
      // transition 2
      #pragma unroll
      for (int c5 = 0; c5 < 5; ++c5)
        hf[c5] = make_bfrag(acc[2 * c5], acc[2 * c5 + 1], srcA, srcB, glo);
      // L3
      f32x4 a3[4];
      #pragma unroll
      for (int tn = 0; tn < 4; ++tn)
        a3[tn] = *(const f32x4*)(rb3 + tn * 16 + nrow);
      #pragma unroll
      for (int c5 = 0; c5 < 5; ++c5)
        #pragma unroll
        for (int tn = 0; tn < 4; ++tn)
          a3[tn] = MFMA16(W3p[(size_t)(c5 * 4 + tn) * 64 + lane], hf[c5], a3[tn]);
      // epilogue
      float* Ro = outR + (size_t)bi * 8192 + (size_t)(rowbase + i) * 64;
      #pragma unroll
      for (int tn = 0; tn < 4; ++tn) {
        f32x4 ov;
        #pragma unroll
        for (int r = 0; r < 4; ++r) ov[r] = sig5(a3[tn][r]);
        *(f32x4*)(Ro + tn * 16 + nrow) = ov;
      }
    }
  } else {
    const f16x8* W2p = (const f16x8*)(Wb);          // QW2
    const f16x8* W3p = (const f16x8*)(Wb + 25600);  // QW3
    // ---- Q branch: 4 chunks per wave ----
    #pragma unroll 1
    for (int s = 0; s < 4; ++s) {
      const int q = w * 4 + s;
      const int b = q >> 3, rowbase = (q & 7) * 16;
      const size_t row = (size_t)(b * 128 + rowbase + i);
      f32x4 acc[10];
      #pragma unroll
      for (int tn = 0; tn < 10; ++tn)
        acc[tn] = *(const f32x4*)(e1q + b * 160 + tn * 16 + nrow);
      const f16x8* W1g = (const f16x8*)(wpk + OFF_QW1);
      #pragma unroll
      for (int c = 0; c < 8; ++c) {
        f16x8 x;
        if (c < 4)      x = ld8(Q + row * 128 + c * 32 + g * 8);
        else if (c < 6) x = ld8max(red0p + row * 64 + (c - 4) * 32 + g * 8, 65536);
        else            x = ld8(red1 + row * 64 + (c - 6) * 32 + g * 8);
        #pragma unroll
        for (int tn = 0; tn < 10; ++tn)
          acc[tn] = MFMA16(W1g[(size_t)(c * 10 + tn) * 64 + lane], x, acc[tn]);
      }
      f16x8 hf[5];
      #pragma unroll
      for (int c5 = 0; c5 < 5; ++c5)
        hf[c5] = make_bfrag(acc[2 * c5], acc[2 * c5 + 1], srcA, srcB, glo);
      #pragma unroll
      for (int tn = 0; tn < 10; ++tn) {
        const int nb = tn * 16 + nrow;
        f32x4 bv = {0.f, 0.f, 0.f, 0.f};
        if (nb < 132) bv = *(const f32x4*)(qb2 + nb);
        acc[tn] = bv;
      }
      #pragma unroll
      for (int c5 = 0; c5 < 5; ++c5)
        #pragma unroll
        for (int tn = 0; tn < 10; ++tn)
          acc[tn] = MFMA16(W2p[(size_t)(c5 * 10 + tn) * 64 + lane], hf[c5], acc[tn]);
      #pragma unroll
      for (int c5 = 0; c5 < 5; ++c5)
        hf[c5] = make_bfrag(acc[2 * c5], acc[2 * c5 + 1], srcA, srcB, glo);
      f32x4 a3[4];
      #pragma unroll
      for (int tn = 0; tn < 4; ++tn)
        a3[tn] = *(const f32x4*)(qb3 + tn * 16 + nrow);
      #pragma unroll
      for (int c5 = 0; c5 < 5; ++c5)
        #pragma unroll
        for (int tn = 0; tn < 4; ++tn)
          a3[tn] = MFMA16(W3p[(size_t)(c5 * 4 + tn) * 64 + lane], hf[c5], a3[tn]);
      float* Qo = outQ + row * 64;
      #pragma unroll
      for (int tn = 0; tn < 4; ++tn) {
        f32x4 ov;
        #pragma unroll
        for (int r = 0; r < 4; ++r) ov[r] = sig5(a3[tn][r]);
        *(f32x4*)(Qo + tn * 16 + nrow) = ov;
      }
    }
    // ---- P branch: one wave, fully global weights ----
    if (w == 15) {
      f32x4 acc[10];
      #pragma unroll
      for (int tn = 0; tn < 10; ++tn) {
        const int nb = tn * 16 + nrow;
        f32x4 cv = {0.f, 0.f, 0.f, 0.f};
        if (nb < 132) cv = *(const f32x4*)(pb1 + nb);
        acc[tn] = cv;
      }
      const f16x8* W1g = (const f16x8*)(wpk + OFF_PW1);
      const int rr = i & 7;
      #pragma unroll
      for (int c = 0; c < 8; ++c) {
        const float* sp = (c < 4) ? (qmax + rr * 128 + c * 32 + g * 8)
                                  : (P + rr * 128 + (c - 4) * 32 + g * 8);
        const f16x8 x = ld8(sp);
        #pragma unroll
        for (int tn = 0; tn < 10; ++tn)
          acc[tn] = MFMA16(W1g[(size_t)(c * 10 + tn) * 64 + lane], x, acc[tn]);
      }
      f16x8 hf[5];
      #pragma unroll
      for (int c5 = 0; c5 < 5; ++c5)
        hf[c5] = make_bfrag(acc[2 * c5], acc[2 * c5 + 1], srcA, srcB, glo);
      const f16x8* W2g = (const f16x8*)(wpk + OFF_PW2);
      #pragma unroll
      for (int tn = 0; tn < 10; ++tn) {
        const int nb = tn * 16 + nrow;
        f32x4 bv = {0.f, 0.f, 0.f, 0.f};
        if (nb < 132) bv = *(const f32x4*)(pb2 + nb);
        acc[tn] = bv;
      }
      #pragma unroll
      for (int c5 = 0; c5 < 5; ++c5)
        #pragma unroll
        for (int tn = 0; tn < 10; ++tn)
          acc[tn] = MFMA16(W2g[(size_t)(c5 * 10 + tn) * 64 + lane], hf[c5], acc[tn]);
      #pragma unroll
      for (int c5 = 0; c5 < 5; ++c5)
        hf[c5] = make_bfrag(acc[2 * c5], acc[2 * c5 + 1], srcA, srcB, glo);
      const f16x8* W3g = (const f16x8*)(wpk + OFF_PW3);
      f32x4 a3[4];
      #pragma unroll
      for (int tn = 0; tn < 4; ++tn)
        a3[tn] = *(const f32x4*)(pb3 + tn * 16 + nrow);
      #pragma unroll
      for (int c5 = 0; c5 < 5; ++c5)
        #pragma unroll
        for (int tn = 0; tn < 4; ++tn)
          a3[tn] = MFMA16(W3g[(size_t)(c5 * 4 + tn) * 64 + lane], hf[c5], a3[tn]);
      if (i < 8) {
        #pragma unroll
        for (int tn = 0; tn < 4; ++tn) {
          f32x4 ov;
          #pragma unroll
          for (int r = 0; r < 4; ++r) ov[r] = sig5(a3[tn][r]);
          *(f32x4*)(outP + (size_t)i * 64 + tn * 16 + nrow) = ov;
        }
      }
    }
  }
}

extern "C" void kernel_launch(void* const* d_in, const int* in_sizes, int n_in,
                              void* d_out, int out_size, void* d_ws, size_t ws_size,
                              hipStream_t stream) {
  (void)in_sizes; (void)n_in; (void)out_size; (void)ws_size;
  InPtrs ip;
  for (int i = 0; i < 21; ++i) ip.p[i] = (const float*)d_in[i];

  char* ws = (char*)d_ws;
  f16* wpk = (f16*)ws;
  float* wsf = (float*)(ws + PACK_BYTES);
  float* c1 = wsf;
  float* d1 = wsf + 163840;
  float* e1q = wsf + 327680;
  float* qmax = wsf + 328960;
  float* red0p = wsf + 329984;   // 2 x 65536 partials
  float* red1 = wsf + 461056;

  float* outP = (float*)d_out;
  float* outQ = outP + 512;
  float* outR = outP + 66048;

  prep_kernel<<<dim3(PREP_BLOCKS), dim3(256), 0, stream>>>(ip, wpk, c1, d1, e1q, qmax,
                                                           red0p, red1);
  fused_kernel<<<dim3(256), dim3(1024), 0, stream>>>((const float*)d_in[2], c1, d1,
      (const float*)d_in[18], (const float*)d_in[20], wpk, outR,
      (const float*)d_in[0], (const float*)d_in[1],
      (const float*)d_in[12], (const float*)d_in[14],
      (const float*)d_in[4], (const float*)d_in[6], (const float*)d_in[8],
      e1q, qmax, red0p, red1, outP, outQ);
}

// Round 9
// 491.318 us; speedup vs baseline: 1.3150x; 1.3150x over previous
//
#include <hip/hip_runtime.h>

typedef _Float16 f16;
typedef f16 f16x8 __attribute__((ext_vector_type(8)));
typedef float f32x4 __attribute__((ext_vector_type(4)));
typedef float f32x2 __attribute__((ext_vector_type(2)));
typedef unsigned u32;

#define MFMA16(a, b, c) __builtin_amdgcn_mfma_f32_16x16x32_f16(a, b, c, 0, 0, 0)

// packed-weight offsets in f16 elements within d_ws (16x16x32 frag layout)
// RW2|RW3 contiguous 70KB at OFF_RW2; QW2|QW3 contiguous 70KB at OFF_QW2.
#define OFF_RW1A 0
#define OFF_RW2  10240
#define OFF_RW3  35840
#define OFF_QW1  46080
#define OFF_QW2  87040
#define OFF_QW3  112640
#define OFF_PW1  122880
#define OFF_PW2  163840
#define OFF_PW3  189440
#define PACK_BYTES 399360   // 199680 f16

// prep grid: [0,256) red0 partials | [256,355) pack | [355,363) qmax
//            [363,371) e1q | [371,627) c1/d1 | [627,1651) red1
#define PREP_BLOCKS 1651

struct InPtrs { const float* p[21]; };

__device__ const int g_mSrc[9] = {15, 17, 19, 9, 11, 13, 3, 5, 7};
__device__ const int g_mK0[9]  = {0, 0, 0, 128, 0, 0, 0, 0, 0};
__device__ const int g_mK[9]   = {64, 132, 132, 256, 132, 132, 256, 132, 132};
__device__ const int g_mN[9]   = {132, 132, 64, 132, 132, 64, 132, 132, 64};
__device__ const int g_mNT[9]  = {10, 10, 4, 10, 10, 4, 10, 10, 4};
__device__ const int g_mDst[9] = {OFF_RW1A, OFF_RW2, OFF_RW3, OFF_QW1, OFF_QW2, OFF_QW3,
                                  OFF_PW1, OFF_PW2, OFF_PW3};
__device__ const int g_mBlk0[9] = {256, 261, 274, 279, 299, 312, 317, 337, 350};

__global__ __launch_bounds__(256) void prep_kernel(InPtrs in, f16* __restrict__ wpk,
    float* __restrict__ c1, float* __restrict__ d1, float* __restrict__ e1q,
    float* __restrict__ qmax, float* __restrict__ red0p, float* __restrict__ red1)
{
  __shared__ float sbuf[1024];
  const int mb = blockIdx.x, t = threadIdx.x;

  if (mb < 256) {
    // red0 partial: max over 64 i's; block = (b, j-oct, i-half). Contiguous 2KB/i.
    const int b = mb >> 5, jo = (mb >> 1) & 15, ih = mb & 1;
    const float* base = in.p[2] + (size_t)b * 1048576 + (size_t)ih * 64 * 8192
                        + (size_t)jo * 512 + t * 2;
    f32x2 m[8];
    #pragma unroll
    for (int u = 0; u < 8; ++u) { m[u][0] = -3.4e38f; m[u][1] = -3.4e38f; }
    for (int i = 0; i < 64; i += 8) {
      #pragma unroll
      for (int u = 0; u < 8; ++u) {
        f32x2 v = *(const f32x2*)(base + (size_t)(i + u) * 8192);
        m[u][0] = fmaxf(m[u][0], v[0]);
        m[u][1] = fmaxf(m[u][1], v[1]);
      }
    }
    #pragma unroll
    for (int s = 4; s > 0; s >>= 1)
      #pragma unroll
      for (int u = 0; u < 4; ++u)
        if (u < s) {
          m[u][0] = fmaxf(m[u][0], m[u + s][0]);
          m[u][1] = fmaxf(m[u][1], m[u + s][1]);
        }
    *(f32x2*)(red0p + (size_t)ih * 65536 +
              ((size_t)(b * 128 + jo * 8 + (t >> 5))) * 64 + ((t * 2) & 63)) = m[0];
  } else if (mb < 355) {
    // weight pack into 16x16x32 MFMA fragment layout
    int mi = 8;
    while (mi > 0 && mb < g_mBlk0[mi]) --mi;
    const int NT = g_mNT[mi], K = g_mK[mi], N = g_mN[mi], K0 = g_mK0[mi];
    const int L = (mb - g_mBlk0[mi]) * 256 + t;
    const int lanes = ((K + 31) >> 5) * NT * 64;
    if (L < lanes) {
      const int lane = L & 63, tile = L >> 6;
      const int kk = tile / NT, nn = tile % NT;
      const float* src = in.p[g_mSrc[mi]];
      const int n = nn * 16 + (lane & 15);
      const int kb = kk * 32 + ((lane >> 4) << 3);
      f16x8 v;
      #pragma unroll
      for (int u = 0; u < 8; ++u) {
        const int k = kb + u;
        float f = (k < K && n < N) ? src[(size_t)(K0 + k) * N + n] : 0.f;
        v[u] = (f16)f;
      }
      *(f16x8*)(wpk + g_mDst[mi] + (size_t)L * 8) = v;
    }
  } else if (mb < 363) {
    // qmax[b,d] = max_i Q[b,i,d]
    const int b = mb - 355;
    const float* Qb = in.p[1] + (size_t)b * 128 * 128;
    const int d = t & 127, g = t >> 7;
    float m0 = -3.4e38f, m1 = m0, m2 = m0, m3 = m0;
    #pragma unroll
    for (int v = 0; v < 16; ++v) {
      const int i = g * 64 + v * 4;
      m0 = fmaxf(m0, Qb[(size_t)(i + 0) * 128 + d]);
      m1 = fmaxf(m1, Qb[(size_t)(i + 1) * 128 + d]);
      m2 = fmaxf(m2, Qb[(size_t)(i + 2) * 128 + d]);
      m3 = fmaxf(m3, Qb[(size_t)(i + 3) * 128 + d]);
    }
    sbuf[g * 128 + d] = fmaxf(fmaxf(m0, m1), fmaxf(m2, m3));
    __syncthreads();
    if (t < 128) qmax[b * 128 + t] = fmaxf(sbuf[t], sbuf[128 + t]);
  } else if (mb < 371) {
    // e1q[b,n] = P[b] . q_w1[0:128] + q_b1
    const int b = mb - 363;
    const float* P = in.p[0]; const float* qw1 = in.p[9]; const float* qb1 = in.p[10];
    if (t < 160) {
      float a = 0.f;
      if (t < 132) {
        float a0 = 0.f, a1 = 0.f, a2 = 0.f, a3 = 0.f;
        for (int k = 0; k < 128; k += 4) {
          a0 += P[b * 128 + k + 0] * qw1[(size_t)(k + 0) * 132 + t];
          a1 += P[b * 128 + k + 1] * qw1[(size_t)(k + 1) * 132 + t];
          a2 += P[b * 128 + k + 2] * qw1[(size_t)(k + 2) * 132 + t];
          a3 += P[b * 128 + k + 3] * qw1[(size_t)(k + 3) * 132 + t];
        }
        a = qb1[t] + (a0 + a1) + (a2 + a3);
      }
      e1q[b * 160 + t] = a;
    }
  } else if (mb < 627) {
    // c1/d1 (r-branch folded Q contributions), 4 Q-rows per block
    const int blk = mb - 371;
    const float* Q = in.p[1]; const float* rw1 = in.p[15]; const float* rb1 = in.p[16];
    for (int o = t; o < 512; o += 256) sbuf[o] = Q[(size_t)blk * 512 + o];
    __syncthreads();
    if (t < 160) {
      float cc[4], dd[4];
      #pragma unroll
      for (int r = 0; r < 4; ++r) { cc[r] = 0.f; dd[r] = 0.f; }
      if (t < 132) {
        const float bb = rb1[t];
        #pragma unroll
        for (int r = 0; r < 4; ++r) cc[r] = bb;
        for (int k = 0; k < 128; ++k) {
          const float wc = rw1[(size_t)(192 + k) * 132 + t];
          const float wd = rw1[(size_t)(64 + k) * 132 + t];
          #pragma unroll
          for (int r = 0; r < 4; ++r) {
            cc[r] += sbuf[r * 128 + k] * wc;
            dd[r] += sbuf[r * 128 + k] * wd;
          }
        }
      }
      for (int r = 0; r < 4; ++r) {
        c1[(size_t)(blk * 4 + r) * 160 + t] = cc[r];
        d1[(size_t)(blk * 4 + r) * 160 + t] = dd[r];
      }
    }
  } else {
    // red1[b,i,d] = max_j R[b,i,j,d]; one block per (b,i); contiguous loads.
    const int bi = mb - 627;
    const int d2 = t & 31, jg = t >> 5;
    const float* base = in.p[2] + (size_t)bi * 8192 + (size_t)jg * 1024 + d2 * 2;
    f32x2 m[4];
    #pragma unroll
    for (int u = 0; u < 4; ++u) { m[u][0] = -3.4e38f; m[u][1] = -3.4e38f; }
    #pragma unroll
    for (int v = 0; v < 16; v += 4) {
      #pragma unroll
      for (int u = 0; u < 4; ++u) {
        f32x2 vv = *(const f32x2*)(base + (size_t)(v + u) * 64);
        m[u][0] = fmaxf(m[u][0], vv[0]);
        m[u][1] = fmaxf(m[u][1], vv[1]);
      }
    }
    m[0][0] = fmaxf(fmaxf(m[0][0], m[1][0]), fmaxf(m[2][0], m[3][0]));
    m[0][1] = fmaxf(fmaxf(m[0][1], m[1][1]), fmaxf(m[2][1], m[3][1]));
    sbuf[jg * 64 + d2 * 2] = m[0][0];
    sbuf[jg * 64 + d2 * 2 + 1] = m[0][1];
    __syncthreads();
    if (t < 64) {
      float mm = sbuf[t];
      #pragma unroll
      for (int g2 = 1; g2 < 8; ++g2) mm = fmaxf(mm, sbuf[g2 * 64 + t]);
      red1[(size_t)bi * 64 + t] = mm;
    }
  }
}

__device__ __forceinline__ float sig5(float x) {
  return 1.f / (1.f + __expf(-5.f * x));
}

__device__ __forceinline__ u32 pk2(float a, float b) {
  typedef __fp16 fp16x2 __attribute__((ext_vector_type(2)));
  union { fp16x2 h; u32 u; } cv;
  cv.h = __builtin_amdgcn_cvt_pkrtz(a, b);
  return cv.u;
}

__device__ __forceinline__ f16x8 ld8(const float* p) {
  f32x4 v0 = *(const f32x4*)p, v1 = *(const f32x4*)(p + 4);
  union { u32 w[4]; f16x8 v; } U;
  U.w[0] = pk2(v0[0], v0[1]); U.w[1] = pk2(v0[2], v0[3]);
  U.w[2] = pk2(v1[0], v1[1]); U.w[3] = pk2(v1[2], v1[3]);
  return U.v;
}

__device__ __forceinline__ f16x8 ld8max(const float* p, int stride) {
  f32x4 a0 = *(const f32x4*)p, a1 = *(const f32x4*)(p + 4);
  f32x4 b0 = *(const f32x4*)(p + stride), b1 = *(const f32x4*)(p + stride + 4);
  union { u32 w[4]; f16x8 v; } U;
  U.w[0] = pk2(fmaxf(a0[0], b0[0]), fmaxf(a0[1], b0[1]));
  U.w[1] = pk2(fmaxf(a0[2], b0[2]), fmaxf(a0[3], b0[3]));
  U.w[2] = pk2(fmaxf(a1[0], b1[0]), fmaxf(a1[1], b1[1]));
  U.w[3] = pk2(fmaxf(a1[2], b1[2]), fmaxf(a1[3], b1[3]));
  return U.v;
}

// Layer-transition: build next-layer B-frag from two D-tiles entirely in regs.
// dest lane (g,i) word pair u/4: from lane ((2g + u/4)&3)*16 + i, tile 2c+(g>>1).
__device__ __forceinline__ f16x8 make_bfrag(const f32x4 ta, const f32x4 tb,
                                            int srcA, int srcB, bool glo) {
  u32 a0 = pk2(fmaxf(ta[0], 0.f), fmaxf(ta[1], 0.f));
  u32 a1 = pk2(fmaxf(ta[2], 0.f), fmaxf(ta[3], 0.f));
  u32 b0 = pk2(fmaxf(tb[0], 0.f), fmaxf(tb[1], 0.f));
  u32 b1 = pk2(fmaxf(tb[2], 0.f), fmaxf(tb[3], 0.f));
  u32 aA0 = (u32)__shfl((int)a0, srcA), aA1 = (u32)__shfl((int)a1, srcA);
  u32 bA0 = (u32)__shfl((int)b0, srcA), bA1 = (u32)__shfl((int)b1, srcA);
  u32 aB0 = (u32)__shfl((int)a0, srcB), aB1 = (u32)__shfl((int)a1, srcB);
  u32 bB0 = (u32)__shfl((int)b0, srcB), bB1 = (u32)__shfl((int)b1, srcB);
  union { u32 w[4]; f16x8 v; } U;
  U.w[0] = glo ? aA0 : bA0;
  U.w[1] = glo ? aA1 : bA1;
  U.w[2] = glo ? aB0 : bB0;
  U.w[3] = glo ? aB1 : bB1;
  return U.v;
}

// ---------------------------------------------------------------------------
// fused kernel: 258 blocks x 512 threads (8 waves). launch_bounds(512,4):
// 2 blocks/CU (16 waves, 4/SIMD, 128-VGPR cap). LDS = 70KB: W2|W3 staged once
// (x2 blocks = 140KB <= 160KB). One barrier total; waves then run free.
// Blocks [0,256): R branch, 32 chunks of 16 rows each (w*4+s).
// Blocks 256,257: Q branch (32 chunks each); block 257 wave 7 also does P.
// ---------------------------------------------------------------------------
__global__ __launch_bounds__(512, 4) void fused_kernel(
    const float* __restrict__ R, const float* __restrict__ c1, const float* __restrict__ d1,
    const float* __restrict__ rb2, const float* __restrict__ rb3,
    const f16* __restrict__ wpk, float* __restrict__ outR,
    const float* __restrict__ P, const float* __restrict__ Q,
    const float* __restrict__ qb2, const float* __restrict__ qb3,
    const float* __restrict__ pb1, const float* __restrict__ pb2, const float* __restrict__ pb3,
    const float* __restrict__ e1q, const float* __restrict__ qmax,
    const float* __restrict__ red0p, const float* __restrict__ red1,
    float* __restrict__ outP, float* __restrict__ outQ)
{
  __shared__ f16 Wb[35840];   // 70 KB: [W2 | W3]
  const int t = threadIdx.x, lane = t & 63, w = t >> 6;
  const int g = lane >> 4, i = lane & 15;
  const int nrow = g * 4;
  const bool glo = (g < 2);
  const int srcA = ((2 * g) & 3) * 16 + i;
  const int srcB = ((2 * g + 1) & 3) * 16 + i;
  const int bk = blockIdx.x;
  const bool isR = (bk < 256);

  {
    const f16* src = wpk + (isR ? OFF_RW2 : OFF_QW2);
    for (int idx = t * 8; idx < 35840; idx += 4096)
      *(f16x8*)(&Wb[idx]) = *(const f16x8*)(src + idx);
  }
  __syncthreads();

  const f16x8* W2p = (const f16x8*)(Wb);          // 50 frags
  const f16x8* W3p = (const f16x8*)(Wb + 25600);  // 20 frags

  if (isR) {
    const f16x8* W1g = (const f16x8*)(wpk + OFF_RW1A);
    #pragma unroll 1
    for (int s = 0; s < 4; ++s) {
      const int chunk = bk * 32 + w * 4 + s;
      const int bi = chunk >> 3, rowbase = (chunk & 7) * 16;
      const int b = bi >> 7;
      const float* c1r = c1 + (size_t)bi * 160;
      const float* d1r = d1 + ((size_t)(b * 128 + rowbase + i)) * 160;
      f32x4 acc[10];
      #pragma unroll
      for (int tn = 0; tn < 10; ++tn)
        acc[tn] = *(const f32x4*)(c1r + tn * 16 + nrow)
                + *(const f32x4*)(d1r + tn * 16 + nrow);
      const float* Rb = R + (size_t)bi * 8192 + (size_t)(rowbase + i) * 64;
      #pragma unroll
      for (int c = 0; c < 2; ++c) {
        const f16x8 x = ld8(Rb + c * 32 + g * 8);
        #pragma unroll
        for (int tn = 0; tn < 10; ++tn)
          acc[tn] = MFMA16(W1g[(size_t)(c * 10 + tn) * 64 + lane], x, acc[tn]);
      }
      f16x8 hf[5];
      #pragma unroll
      for (int c5 = 0; c5 < 5; ++c5)
        hf[c5] = make_bfrag(acc[2 * c5], acc[2 * c5 + 1], srcA, srcB, glo);
      #pragma unroll
      for (int tn = 0; tn < 10; ++tn) {
        const int nb = tn * 16 + nrow;
        f32x4 bv = {0.f, 0.f, 0.f, 0.f};
        if (nb < 132) bv = *(const f32x4*)(rb2 + nb);
        acc[tn] = bv;
      }
      #pragma unroll
      for (int c5 = 0; c5 < 5; ++c5)
        #pragma unroll
        for (int tn = 0; tn < 10; ++tn)
          acc[tn] = MFMA16(W2p[(size_t)(c5 * 10 + tn) * 64 + lane], hf[c5], acc[tn]);
      #pragma unroll
      for (int c5 = 0; c5 < 5; ++c5)
        hf[c5] = make_bfrag(acc[2 * c5], acc[2 * c5 + 1], srcA, srcB, glo);
      f32x4 a3[4];
      #pragma unroll
      for (int tn = 0; tn < 4; ++tn)
        a3[tn] = *(const f32x4*)(rb3 + tn * 16 + nrow);
      #pragma unroll
      for (int c5 = 0; c5 < 5; ++c5)
        #pragma unroll
        for (int tn = 0; tn < 4; ++tn)
          a3[tn] = MFMA16(W3p[(size_t)(c5 * 4 + tn) * 64 + lane], hf[c5], a3[tn]);
      float* Ro = outR + (size_t)bi * 8192 + (size_t)(rowbase + i) * 64;
      #pragma unroll
      for (int tn = 0; tn < 4; ++tn) {
        f32x4 ov;
        #pragma unroll
        for (int r = 0; r < 4; ++r) ov[r] = sig5(a3[tn][r]);
        *(f32x4*)(Ro + tn * 16 + nrow) = ov;
      }
    }
  } else {
    const f16x8* W1g = (const f16x8*)(wpk + OFF_QW1);
    #pragma unroll 1
    for (int s = 0; s < 4; ++s) {
      const int q = (bk - 256) * 32 + w * 4 + s;   // 0..63
      const int b = q >> 3, rowbase = (q & 7) * 16;
      const size_t row = (size_t)(b * 128 + rowbase + i);
      f32x4 acc[10];
      #pragma unroll
      for (int tn = 0; tn < 10; ++tn)
        acc[tn] = *(const f32x4*)(e1q + b * 160 + tn * 16 + nrow);
      #pragma unroll
      for (int c = 0; c < 8; ++c) {
        f16x8 x;
        if (c < 4)      x = ld8(Q + row * 128 + c * 32 + g * 8);
        else if (c < 6) x = ld8max(red0p + row * 64 + (c - 4) * 32 + g * 8, 65536);
        else            x = ld8(red1 + row * 64 + (c - 6) * 32 + g * 8);
        #pragma unroll
        for (int tn = 0; tn < 10; ++tn)
          acc[tn] = MFMA16(W1g[(size_t)(c * 10 + tn) * 64 + lane], x, acc[tn]);
      }
      f16x8 hf[5];
      #pragma unroll
      for (int c5 = 0; c5 < 5; ++c5)
        hf[c5] = make_bfrag(acc[2 * c5], acc[2 * c5 + 1], srcA, srcB, glo);
      #pragma unroll
      for (int tn = 0; tn < 10; ++tn) {
        const int nb = tn * 16 + nrow;
        f32x4 bv = {0.f, 0.f, 0.f, 0.f};
        if (nb < 132) bv = *(const f32x4*)(qb2 + nb);
        acc[tn] = bv;
      }
      #pragma unroll
      for (int c5 = 0; c5 < 5; ++c5)
        #pragma unroll
        for (int tn = 0; tn < 10; ++tn)
          acc[tn] = MFMA16(W2p[(size_t)(c5 * 10 + tn) * 64 + lane], hf[c5], acc[tn]);
      #pragma unroll
      for (int c5 = 0; c5 < 5; ++c5)
        hf[c5] = make_bfrag(acc[2 * c5], acc[2 * c5 + 1], srcA, srcB, glo);
      f32x4 a3[4];
      #pragma unroll
      for (int tn = 0; tn < 4; ++tn)
        a3[tn] = *(const f32x4*)(qb3 + tn * 16 + nrow);
      #pragma unroll
      for (int c5 = 0; c5 < 5; ++c5)
        #pragma unroll
        for (int tn = 0; tn < 4; ++tn)
          a3[tn] = MFMA16(W3p[(size_t)(c5 * 4 + tn) * 64 + lane], hf[c5], a3[tn]);
      float* Qo = outQ + row * 64;
      #pragma unroll
      for (int tn = 0; tn < 4; ++tn) {
        f32x4 ov;
        #pragma unroll
        for (int r = 0; r < 4; ++r) ov[r] = sig5(a3[tn][r]);
        *(f32x4*)(Qo + tn * 16 + nrow) = ov;
      }
    }
    // ---- P branch: one wave, global weights ----
    if (bk == 257 && w == 7) {
      f32x4 acc[10];
      #pragma unroll
      for (int tn = 0; tn < 10; ++tn) {
        const int nb = tn * 16 + nrow;
        f32x4 cv = {0.f, 0.f, 0.f, 0.f};
        if (nb < 132) cv = *(const f32x4*)(pb1 + nb);
        acc[tn] = cv;
      }
      const f16x8* PW1 = (const f16x8*)(wpk + OFF_PW1);
      const int rr = i & 7;
      #pragma unroll
      for (int c = 0; c < 8; ++c) {
        const float* sp = (c < 4) ? (qmax + rr * 128 + c * 32 + g * 8)
                                  : (P + rr * 128 + (c - 4) * 32 + g * 8);
        const f16x8 x = ld8(sp);
        #pragma unroll
        for (int tn = 0; tn < 10; ++tn)
          acc[tn] = MFMA16(PW1[(size_t)(c * 10 + tn) * 64 + lane], x, acc[tn]);
      }
      f16x8 hf[5];
      #pragma unroll
      for (int c5 = 0; c5 < 5; ++c5)
        hf[c5] = make_bfrag(acc[2 * c5], acc[2 * c5 + 1], srcA, srcB, glo);
      const f16x8* PW2 = (const f16x8*)(wpk + OFF_PW2);
      #pragma unroll
      for (int tn = 0; tn < 10; ++tn) {
        const int nb = tn * 16 + nrow;
        f32x4 bv = {0.f, 0.f, 0.f, 0.f};
        if (nb < 132) bv = *(const f32x4*)(pb2 + nb);
        acc[tn] = bv;
      }
      #pragma unroll
      for (int c5 = 0; c5 < 5; ++c5)
        #pragma unroll
        for (int tn = 0; tn < 10; ++tn)
          acc[tn] = MFMA16(PW2[(size_t)(c5 * 10 + tn) * 64 + lane], hf[c5], acc[tn]);
      #pragma unroll
      for (int c5 = 0; c5 < 5; ++c5)
        hf[c5] = make_bfrag(acc[2 * c5], acc[2 * c5 + 1], srcA, srcB, glo);
      const f16x8* PW3 = (const f16x8*)(wpk + OFF_PW3);
      f32x4 a3[4];
      #pragma unroll
      for (int tn = 0; tn < 4; ++tn)
        a3[tn] = *(const f32x4*)(pb3 + tn * 16 + nrow);
      #pragma unroll
      for (int c5 = 0; c5 < 5; ++c5)
        #pragma unroll
        for (int tn = 0; tn < 4; ++tn)
          a3[tn] = MFMA16(PW3[(size_t)(c5 * 4 + tn) * 64 + lane], hf[c5], a3[tn]);
      if (i < 8) {
        #pragma unroll
        for (int tn = 0; tn < 4; ++tn) {
          f32x4 ov;
          #pragma unroll
          for (int r = 0; r < 4; ++r) ov[r] = sig5(a3[tn][r]);
          *(f32x4*)(outP + (size_t)i * 64 + tn * 16 + nrow) = ov;
        }
      }
    }
  }
}

extern "C" void kernel_launch(void* const* d_in, const int* in_sizes, int n_in,
                              void* d_out, int out_size, void* d_ws, size_t ws_size,
                              hipStream_t stream) {
  (void)in_sizes; (void)n_in; (void)out_size; (void)ws_size;
  InPtrs ip;
  for (int i = 0; i < 21; ++i) ip.p[i] = (const float*)d_in[i];

  char* ws = (char*)d_ws;
  f16* wpk = (f16*)ws;
  float* wsf = (float*)(ws + PACK_BYTES);
  float* c1 = wsf;
  float* d1 = wsf + 163840;
  float* e1q = wsf + 327680;
  float* qmax = wsf + 328960;
  float* red0p = wsf + 329984;   // 2 x 65536 partials
  float* red1 = wsf + 461056;

  float* outP = (float*)d_out;
  float* outQ = outP + 512;
  float* outR = outP + 66048;

  prep_kernel<<<dim3(PREP_BLOCKS), dim3(256), 0, stream>>>(ip, wpk, c1, d1, e1q, qmax,
                                                           red0p, red1);
  fused_kernel<<<dim3(258), dim3(512), 0, stream>>>((const float*)d_in[2], c1, d1,
      (const float*)d_in[18], (const float*)d_in[20], wpk, outR,
      (const float*)d_in[0], (const float*)d_in[1],
      (const float*)d_in[12], (const float*)d_in[14],
      (const float*)d_in[4], (const float*)d_in[6], (const float*)d_in[8],
      e1q, qmax, red0p, red1, outP, outQ);
}

// Round 10
// 136.622 us; speedup vs baseline: 4.7290x; 3.5962x over previous
//
#include <hip/hip_runtime.h>

typedef _Float16 f16;
typedef f16 f16x8 __attribute__((ext_vector_type(8)));
typedef float f32x4 __attribute__((ext_vector_type(4)));
typedef float f32x2 __attribute__((ext_vector_type(2)));
typedef unsigned u32;

#define MFMA16(a, b, c) __builtin_amdgcn_mfma_f32_16x16x32_f16(a, b, c, 0, 0, 0)

// packed-weight offsets in f16 elements within d_ws (16x16x32 frag layout)
// RW2|RW3 contiguous 70KB at OFF_RW2; QW2|QW3 contiguous 70KB at OFF_QW2.
#define OFF_RW1A 0
#define OFF_RW2  10240
#define OFF_RW3  35840
#define OFF_QW1  46080
#define OFF_QW2  87040
#define OFF_QW3  112640
#define OFF_PW1  122880
#define OFF_PW2  163840
#define OFF_PW3  189440
#define PACK_BYTES 399360   // 199680 f16

// prep grid: [0,256) red0 partials | [256,355) pack | [355,363) qmax
//            [363,371) e1q | [371,627) c1/d1 | [627,1651) red1
#define PREP_BLOCKS 1651

struct InPtrs { const float* p[21]; };

__device__ const int g_mSrc[9] = {15, 17, 19, 9, 11, 13, 3, 5, 7};
__device__ const int g_mK0[9]  = {0, 0, 0, 128, 0, 0, 0, 0, 0};
__device__ const int g_mK[9]   = {64, 132, 132, 256, 132, 132, 256, 132, 132};
__device__ const int g_mN[9]   = {132, 132, 64, 132, 132, 64, 132, 132, 64};
__device__ const int g_mNT[9]  = {10, 10, 4, 10, 10, 4, 10, 10, 4};
__device__ const int g_mDst[9] = {OFF_RW1A, OFF_RW2, OFF_RW3, OFF_QW1, OFF_QW2, OFF_QW3,
                                  OFF_PW1, OFF_PW2, OFF_PW3};
__device__ const int g_mBlk0[9] = {256, 261, 274, 279, 299, 312, 317, 337, 350};

__global__ __launch_bounds__(256) void prep_kernel(InPtrs in, f16* __restrict__ wpk,
    float* __restrict__ c1, float* __restrict__ d1, float* __restrict__ e1q,
    float* __restrict__ qmax, float* __restrict__ red0p, float* __restrict__ red1)
{
  __shared__ float sbuf[1024];
  const int mb = blockIdx.x, t = threadIdx.x;

  if (mb < 256) {
    // red0 partial: max over 64 i's; block = (b, j-oct, i-half). Contiguous 2KB/i.
    const int b = mb >> 5, jo = (mb >> 1) & 15, ih = mb & 1;
    const float* base = in.p[2] + (size_t)b * 1048576 + (size_t)ih * 64 * 8192
                        + (size_t)jo * 512 + t * 2;
    f32x2 m[8];
    #pragma unroll
    for (int u = 0; u < 8; ++u) { m[u][0] = -3.4e38f; m[u][1] = -3.4e38f; }
    for (int i = 0; i < 64; i += 8) {
      #pragma unroll
      for (int u = 0; u < 8; ++u) {
        f32x2 v = *(const f32x2*)(base + (size_t)(i + u) * 8192);
        m[u][0] = fmaxf(m[u][0], v[0]);
        m[u][1] = fmaxf(m[u][1], v[1]);
      }
    }
    #pragma unroll
    for (int s = 4; s > 0; s >>= 1)
      #pragma unroll
      for (int u = 0; u < 4; ++u)
        if (u < s) {
          m[u][0] = fmaxf(m[u][0], m[u + s][0]);
          m[u][1] = fmaxf(m[u][1], m[u + s][1]);
        }
    *(f32x2*)(red0p + (size_t)ih * 65536 +
              ((size_t)(b * 128 + jo * 8 + (t >> 5))) * 64 + ((t * 2) & 63)) = m[0];
  } else if (mb < 355) {
    // weight pack into 16x16x32 MFMA fragment layout
    int mi = 8;
    while (mi > 0 && mb < g_mBlk0[mi]) --mi;
    const int NT = g_mNT[mi], K = g_mK[mi], N = g_mN[mi], K0 = g_mK0[mi];
    const int L = (mb - g_mBlk0[mi]) * 256 + t;
    const int lanes = ((K + 31) >> 5) * NT * 64;
    if (L < lanes) {
      const int lane = L & 63, tile = L >> 6;
      const int kk = tile / NT, nn = tile % NT;
      const float* src = in.p[g_mSrc[mi]];
      const int n = nn * 16 + (lane & 15);
      const int kb = kk * 32 + ((lane >> 4) << 3);
      f16x8 v;
      #pragma unroll
      for (int u = 0; u < 8; ++u) {
        const int k = kb + u;
        float f = (k < K && n < N) ? src[(size_t)(K0 + k) * N + n] : 0.f;
        v[u] = (f16)f;
      }
      *(f16x8*)(wpk + g_mDst[mi] + (size_t)L * 8) = v;
    }
  } else if (mb < 363) {
    // qmax[b,d] = max_i Q[b,i,d]
    const int b = mb - 355;
    const float* Qb = in.p[1] + (size_t)b * 128 * 128;
    const int d = t & 127, g = t >> 7;
    float m0 = -3.4e38f, m1 = m0, m2 = m0, m3 = m0;
    #pragma unroll
    for (int v = 0; v < 16; ++v) {
      const int i = g * 64 + v * 4;
      m0 = fmaxf(m0, Qb[(size_t)(i + 0) * 128 + d]);
      m1 = fmaxf(m1, Qb[(size_t)(i + 1) * 128 + d]);
      m2 = fmaxf(m2, Qb[(size_t)(i + 2) * 128 + d]);
      m3 = fmaxf(m3, Qb[(size_t)(i + 3) * 128 + d]);
    }
    sbuf[g * 128 + d] = fmaxf(fmaxf(m0, m1), fmaxf(m2, m3));
    __syncthreads();
    if (t < 128) qmax[b * 128 + t] = fmaxf(sbuf[t], sbuf[128 + t]);
  } else if (mb < 371) {
    // e1q[b,n] = P[b] . q_w1[0:128] + q_b1
    const int b = mb - 363;
    const float* P = in.p[0]; const float* qw1 = in.p[9]; const float* qb1 = in.p[10];
    if (t < 160) {
      float a = 0.f;
      if (t < 132) {
        float a0 = 0.f, a1 = 0.f, a2 = 0.f, a3 = 0.f;
        for (int k = 0; k < 128; k += 4) {
          a0 += P[b * 128 + k + 0] * qw1[(size_t)(k + 0) * 132 + t];
          a1 += P[b * 128 + k + 1] * qw1[(size_t)(k + 1) * 132 + t];
          a2 += P[b * 128 + k + 2] * qw1[(size_t)(k + 2) * 132 + t];
          a3 += P[b * 128 + k + 3] * qw1[(size_t)(k + 3) * 132 + t];
        }
        a = qb1[t] + (a0 + a1) + (a2 + a3);
      }
      e1q[b * 160 + t] = a;
    }
  } else if (mb < 627) {
    // c1/d1 (r-branch folded Q contributions), 4 Q-rows per block
    const int blk = mb - 371;
    const float* Q = in.p[1]; const float* rw1 = in.p[15]; const float* rb1 = in.p[16];
    for (int o = t; o < 512; o += 256) sbuf[o] = Q[(size_t)blk * 512 + o];
    __syncthreads();
    if (t < 160) {
      float cc[4], dd[4];
      #pragma unroll
      for (int r = 0; r < 4; ++r) { cc[r] = 0.f; dd[r] = 0.f; }
      if (t < 132) {
        const float bb = rb1[t];
        #pragma unroll
        for (int r = 0; r < 4; ++r) cc[r] = bb;
        for (int k = 0; k < 128; ++k) {
          const float wc = rw1[(size_t)(192 + k) * 132 + t];
          const float wd = rw1[(size_t)(64 + k) * 132 + t];
          #pragma unroll
          for (int r = 0; r < 4; ++r) {
            cc[r] += sbuf[r * 128 + k] * wc;
            dd[r] += sbuf[r * 128 + k] * wd;
          }
        }
      }
      for (int r = 0; r < 4; ++r) {
        c1[(size_t)(blk * 4 + r) * 160 + t] = cc[r];
        d1[(size_t)(blk * 4 + r) * 160 + t] = dd[r];
      }
    }
  } else {
    // red1[b,i,d] = max_j R[b,i,j,d]; one block per (b,i); contiguous loads.
    const int bi = mb - 627;
    const int d2 = t & 31, jg = t >> 5;
    const float* base = in.p[2] + (size_t)bi * 8192 + (size_t)jg * 1024 + d2 * 2;
    f32x2 m[4];
    #pragma unroll
    for (int u = 0; u < 4; ++u) { m[u][0] = -3.4e38f; m[u][1] = -3.4e38f; }
    #pragma unroll
    for (int v = 0; v < 16; v += 4) {
      #pragma unroll
      for (int u = 0; u < 4; ++u) {
        f32x2 vv = *(const f32x2*)(base + (size_t)(v + u) * 64);
        m[u][0] = fmaxf(m[u][0], vv[0]);
        m[u][1] = fmaxf(m[u][1], vv[1]);
      }
    }
    m[0][0] = fmaxf(fmaxf(m[0][0], m[1][0]), fmaxf(m[2][0], m[3][0]));
    m[0][1] = fmaxf(fmaxf(m[0][1], m[1][1]), fmaxf(m[2][1], m[3][1]));
    sbuf[jg * 64 + d2 * 2] = m[0][0];
    sbuf[jg * 64 + d2 * 2 + 1] = m[0][1];
    __syncthreads();
    if (t < 64) {
      float mm = sbuf[t];
      #pragma unroll
      for (int g2 = 1; g2 < 8; ++g2) mm = fmaxf(mm, sbuf[g2 * 64 + t]);
      red1[(size_t)bi * 64 + t] = mm;
    }
  }
}

__device__ __forceinline__ float sig5(float x) {
  return 1.f / (1.f + __expf(-5.f * x));
}

__device__ __forceinline__ u32 pk2(float a, float b) {
  typedef __fp16 fp16x2 __attribute__((ext_vector_type(2)));
  union { fp16x2 h; u32 u; } cv;
  cv.h = __builtin_amdgcn_cvt_pkrtz(a, b);
  return cv.u;
}

__device__ __forceinline__ f16x8 ld8(const float* p) {
  f32x4 v0 = *(const f32x4*)p, v1 = *(const f32x4*)(p + 4);
  union { u32 w[4]; f16x8 v; } U;
  U.w[0] = pk2(v0[0], v0[1]); U.w[1] = pk2(v0[2], v0[3]);
  U.w[2] = pk2(v1[0], v1[1]); U.w[3] = pk2(v1[2], v1[3]);
  return U.v;
}

__device__ __forceinline__ f16x8 ld8max(const float* p, int stride) {
  f32x4 a0 = *(const f32x4*)p, a1 = *(const f32x4*)(p + 4);
  f32x4 b0 = *(const f32x4*)(p + stride), b1 = *(const f32x4*)(p + stride + 4);
  union { u32 w[4]; f16x8 v; } U;
  U.w[0] = pk2(fmaxf(a0[0], b0[0]), fmaxf(a0[1], b0[1]));
  U.w[1] = pk2(fmaxf(a0[2], b0[2]), fmaxf(a0[3], b0[3]));
  U.w[2] = pk2(fmaxf(a1[0], b1[0]), fmaxf(a1[1], b1[1]));
  U.w[3] = pk2(fmaxf(a1[2], b1[2]), fmaxf(a1[3], b1[3]));
  return U.v;
}

// Layer-transition: build next-layer B-frag from two D-tiles entirely in regs.
// dest lane (g,i) word pair u/4: from lane ((2g + u/4)&3)*16 + i, tile 2c+(g>>1).
__device__ __forceinline__ f16x8 make_bfrag(const f32x4 ta, const f32x4 tb,
                                            int srcA, int srcB, bool glo) {
  u32 a0 = pk2(fmaxf(ta[0], 0.f), fmaxf(ta[1], 0.f));
  u32 a1 = pk2(fmaxf(ta[2], 0.f), fmaxf(ta[3], 0.f));
  u32 b0 = pk2(fmaxf(tb[0], 0.f), fmaxf(tb[1], 0.f));
  u32 b1 = pk2(fmaxf(tb[2], 0.f), fmaxf(tb[3], 0.f));
  u32 aA0 = (u32)__shfl((int)a0, srcA), aA1 = (u32)__shfl((int)a1, srcA);
  u32 bA0 = (u32)__shfl((int)b0, srcA), bA1 = (u32)__shfl((int)b1, srcA);
  u32 aB0 = (u32)__shfl((int)a0, srcB), aB1 = (u32)__shfl((int)a1, srcB);
  u32 bB0 = (u32)__shfl((int)b0, srcB), bB1 = (u32)__shfl((int)b1, srcB);
  union { u32 w[4]; f16x8 v; } U;
  U.w[0] = glo ? aA0 : bA0;
  U.w[1] = glo ? aA1 : bA1;
  U.w[2] = glo ? aB0 : bB0;
  U.w[3] = glo ? aB1 : bB1;
  return U.v;
}

// ---------------------------------------------------------------------------
// fused kernel: 516 blocks x 256 threads (4 waves), launch_bounds(256,3)
// (the round-7-proven register budget: ~84 VGPR + AGPR, no spill).
// LDS 70KB: W2|W3 staged once -> 2 blocks/CU (8 waves). One barrier total.
// Blocks [0,4): QP (first, so not scheduled last): 16 Q chunks each;
//   block 3 wave 3 also does P. Blocks [4,516): R, 16 chunks each.
// ---------------------------------------------------------------------------
__global__ __launch_bounds__(256, 3) void fused_kernel(
    const float* __restrict__ R, const float* __restrict__ c1, const float* __restrict__ d1,
    const float* __restrict__ rb2, const float* __restrict__ rb3,
    const f16* __restrict__ wpk, float* __restrict__ outR,
    const float* __restrict__ P, const float* __restrict__ Q,
    const float* __restrict__ qb2, const float* __restrict__ qb3,
    const float* __restrict__ pb1, const float* __restrict__ pb2, const float* __restrict__ pb3,
    const float* __restrict__ e1q, const float* __restrict__ qmax,
    const float* __restrict__ red0p, const float* __restrict__ red1,
    float* __restrict__ outP, float* __restrict__ outQ)
{
  __shared__ f16 Wb[35840];   // 70 KB: [W2 | W3]
  const int t = threadIdx.x, lane = t & 63, w = t >> 6;
  const int g = lane >> 4, i = lane & 15;
  const int nrow = g * 4;
  const bool glo = (g < 2);
  const int srcA = ((2 * g) & 3) * 16 + i;
  const int srcB = ((2 * g + 1) & 3) * 16 + i;
  const int bk = blockIdx.x;
  const bool isR = (bk >= 4);

  {
    const f16* src = wpk + (isR ? OFF_RW2 : OFF_QW2);
    for (int idx = t * 8; idx < 35840; idx += 2048)
      *(f16x8*)(&Wb[idx]) = *(const f16x8*)(src + idx);
  }
  __syncthreads();

  const f16x8* W2p = (const f16x8*)(Wb);          // 50 frags
  const f16x8* W3p = (const f16x8*)(Wb + 25600);  // 20 frags

  if (isR) {
    const f16x8* W1g = (const f16x8*)(wpk + OFF_RW1A);
    #pragma unroll 1
    for (int s = 0; s < 4; ++s) {
      const int chunk = (bk - 4) * 16 + w * 4 + s;
      const int bi = chunk >> 3, rowbase = (chunk & 7) * 16;
      const int b = bi >> 7;
      const float* c1r = c1 + (size_t)bi * 160;
      const float* d1r = d1 + ((size_t)(b * 128 + rowbase + i)) * 160;
      f32x4 acc[10];
      #pragma unroll
      for (int tn = 0; tn < 10; ++tn)
        acc[tn] = *(const f32x4*)(c1r + tn * 16 + nrow)
                + *(const f32x4*)(d1r + tn * 16 + nrow);
      const float* Rb = R + (size_t)bi * 8192 + (size_t)(rowbase + i) * 64;
      #pragma unroll
      for (int c = 0; c < 2; ++c) {
        const f16x8 x = ld8(Rb + c * 32 + g * 8);
        #pragma unroll
        for (int tn = 0; tn < 10; ++tn)
          acc[tn] = MFMA16(W1g[(size_t)(c * 10 + tn) * 64 + lane], x, acc[tn]);
      }
      f16x8 hf[5];
      #pragma unroll
      for (int c5 = 0; c5 < 5; ++c5)
        hf[c5] = make_bfrag(acc[2 * c5], acc[2 * c5 + 1], srcA, srcB, glo);
      #pragma unroll
      for (int tn = 0; tn < 10; ++tn) {
        const int nb = tn * 16 + nrow;
        f32x4 bv = {0.f, 0.f, 0.f, 0.f};
        if (nb < 132) bv = *(const f32x4*)(rb2 + nb);
        acc[tn] = bv;
      }
      #pragma unroll
      for (int c5 = 0; c5 < 5; ++c5)
        #pragma unroll
        for (int tn = 0; tn < 10; ++tn)
          acc[tn] = MFMA16(W2p[(size_t)(c5 * 10 + tn) * 64 + lane], hf[c5], acc[tn]);
      #pragma unroll
      for (int c5 = 0; c5 < 5; ++c5)
        hf[c5] = make_bfrag(acc[2 * c5], acc[2 * c5 + 1], srcA, srcB, glo);
      f32x4 a3[4];
      #pragma unroll
      for (int tn = 0; tn < 4; ++tn)
        a3[tn] = *(const f32x4*)(rb3 + tn * 16 + nrow);
      #pragma unroll
      for (int c5 = 0; c5 < 5; ++c5)
        #pragma unroll
        for (int tn = 0; tn < 4; ++tn)
          a3[tn] = MFMA16(W3p[(size_t)(c5 * 4 + tn) * 64 + lane], hf[c5], a3[tn]);
      float* Ro = outR + (size_t)bi * 8192 + (size_t)(rowbase + i) * 64;
      #pragma unroll
      for (int tn = 0; tn < 4; ++tn) {
        f32x4 ov;
        #pragma unroll
        for (int r = 0; r < 4; ++r) ov[r] = sig5(a3[tn][r]);
        *(f32x4*)(Ro + tn * 16 + nrow) = ov;
      }
    }
  } else {
    const f16x8* W1g = (const f16x8*)(wpk + OFF_QW1);
    #pragma unroll 1
    for (int s = 0; s < 4; ++s) {
      const int q = bk * 16 + w * 4 + s;   // 0..63
      const int b = q >> 3, rowbase = (q & 7) * 16;
      const size_t row = (size_t)(b * 128 + rowbase + i);
      f32x4 acc[10];
      #pragma unroll
      for (int tn = 0; tn < 10; ++tn)
        acc[tn] = *(const f32x4*)(e1q + b * 160 + tn * 16 + nrow);
      #pragma unroll
      for (int c = 0; c < 8; ++c) {
        f16x8 x;
        if (c < 4)      x = ld8(Q + row * 128 + c * 32 + g * 8);
        else if (c < 6) x = ld8max(red0p + row * 64 + (c - 4) * 32 + g * 8, 65536);
        else            x = ld8(red1 + row * 64 + (c - 6) * 32 + g * 8);
        #pragma unroll
        for (int tn = 0; tn < 10; ++tn)
          acc[tn] = MFMA16(W1g[(size_t)(c * 10 + tn) * 64 + lane], x, acc[tn]);
      }
      f16x8 hf[5];
      #pragma unroll
      for (int c5 = 0; c5 < 5; ++c5)
        hf[c5] = make_bfrag(acc[2 * c5], acc[2 * c5 + 1], srcA, srcB, glo);
      #pragma unroll
      for (int tn = 0; tn < 10; ++tn) {
        const int nb = tn * 16 + nrow;
        f32x4 bv = {0.f, 0.f, 0.f, 0.f};
        if (nb < 132) bv = *(const f32x4*)(qb2 + nb);
        acc[tn] = bv;
      }
      #pragma unroll
      for (int c5 = 0; c5 < 5; ++c5)
        #pragma unroll
        for (int tn = 0; tn < 10; ++tn)
          acc[tn] = MFMA16(W2p[(size_t)(c5 * 10 + tn) * 64 + lane], hf[c5], acc[tn]);
      #pragma unroll
      for (int c5 = 0; c5 < 5; ++c5)
        hf[c5] = make_bfrag(acc[2 * c5], acc[2 * c5 + 1], srcA, srcB, glo);
      f32x4 a3[4];
      #pragma unroll
      for (int tn = 0; tn < 4; ++tn)
        a3[tn] = *(const f32x4*)(qb3 + tn * 16 + nrow);
      #pragma unroll
      for (int c5 = 0; c5 < 5; ++c5)
        #pragma unroll
        for (int tn = 0; tn < 4; ++tn)
          a3[tn] = MFMA16(W3p[(size_t)(c5 * 4 + tn) * 64 + lane], hf[c5], a3[tn]);
      float* Qo = outQ + row * 64;
      #pragma unroll
      for (int tn = 0; tn < 4; ++tn) {
        f32x4 ov;
        #pragma unroll
        for (int r = 0; r < 4; ++r) ov[r] = sig5(a3[tn][r]);
        *(f32x4*)(Qo + tn * 16 + nrow) = ov;
      }
    }
    // ---- P branch: one wave, global weights ----
    if (bk == 3 && w == 3) {
      f32x4 acc[10];
      #pragma unroll
      for (int tn = 0; tn < 10; ++tn) {
        const int nb = tn * 16 + nrow;
        f32x4 cv = {0.f, 0.f, 0.f, 0.f};
        if (nb < 132) cv = *(const f32x4*)(pb1 + nb);
        acc[tn] = cv;
      }
      const f16x8* PW1 = (const f16x8*)(wpk + OFF_PW1);
      const int rr = i & 7;
      #pragma unroll
      for (int c = 0; c < 8; ++c) {
        const float* sp = (c < 4) ? (qmax + rr * 128 + c * 32 + g * 8)
                                  : (P + rr * 128 + (c - 4) * 32 + g * 8);
        const f16x8 x = ld8(sp);
        #pragma unroll
        for (int tn = 0; tn < 10; ++tn)
          acc[tn] = MFMA16(PW1[(size_t)(c * 10 + tn) * 64 + lane], x, acc[tn]);
      }
      f16x8 hf[5];
      #pragma unroll
      for (int c5 = 0; c5 < 5; ++c5)
        hf[c5] = make_bfrag(acc[2 * c5], acc[2 * c5 + 1], srcA, srcB, glo);
      const f16x8* PW2 = (const f16x8*)(wpk + OFF_PW2);
      #pragma unroll
      for (int tn = 0; tn < 10; ++tn) {
        const int nb = tn * 16 + nrow;
        f32x4 bv = {0.f, 0.f, 0.f, 0.f};
        if (nb < 132) bv = *(const f32x4*)(pb2 + nb);
        acc[tn] = bv;
      }
      #pragma unroll
      for (int c5 = 0; c5 < 5; ++c5)
        #pragma unroll
        for (int tn = 0; tn < 10; ++tn)
          acc[tn] = MFMA16(PW2[(size_t)(c5 * 10 + tn) * 64 + lane], hf[c5], acc[tn]);
      #pragma unroll
      for (int c5 = 0; c5 < 5; ++c5)
        hf[c5] = make_bfrag(acc[2 * c5], acc[2 * c5 + 1], srcA, srcB, glo);
      const f16x8* PW3 = (const f16x8*)(wpk + OFF_PW3);
      f32x4 a3[4];
      #pragma unroll
      for (int tn = 0; tn < 4; ++tn)
        a3[tn] = *(const f32x4*)(pb3 + tn * 16 + nrow);
      #pragma unroll
      for (int c5 = 0; c5 < 5; ++c5)
        #pragma unroll
        for (int tn = 0; tn < 4; ++tn)
          a3[tn] = MFMA16(PW3[(size_t)(c5 * 4 + tn) * 64 + lane], hf[c5], a3[tn]);
      if (i < 8) {
        #pragma unroll
        for (int tn = 0; tn < 4; ++tn) {
          f32x4 ov;
          #pragma unroll
          for (int r = 0; r < 4; ++r) ov[r] = sig5(a3[tn][r]);
          *(f32x4*)(outP + (size_t)i * 64 + tn * 16 + nrow) = ov;
        }
      }
    }
  }
}

extern "C" void kernel_launch(void* const* d_in, const int* in_sizes, int n_in,
                              void* d_out, int out_size, void* d_ws, size_t ws_size,
                              hipStream_t stream) {
  (void)in_sizes; (void)n_in; (void)out_size; (void)ws_size;
  InPtrs ip;
  for (int i = 0; i < 21; ++i) ip.p[i] = (const float*)d_in[i];

  char* ws = (char*)d_ws;
  f16* wpk = (f16*)ws;
  float* wsf = (float*)(ws + PACK_BYTES);
  float* c1 = wsf;
  float* d1 = wsf + 163840;
  float* e1q = wsf + 327680;
  float* qmax = wsf + 328960;
  float* red0p = wsf + 329984;   // 2 x 65536 partials
  float* red1 = wsf + 461056;

  float* outP = (float*)d_out;
  float* outQ = outP + 512;
  float* outR = outP + 66048;

  prep_kernel<<<dim3(PREP_BLOCKS), dim3(256), 0, stream>>>(ip, wpk, c1, d1, e1q, qmax,
                                                           red0p, red1);
  fused_kernel<<<dim3(516), dim3(256), 0, stream>>>((const float*)d_in[2], c1, d1,
      (const float*)d_in[18], (const float*)d_in[20], wpk, outR,
      (const float*)d_in[0], (const float*)d_in[1],
      (const float*)d_in[12], (const float*)d_in[14],
      (const float*)d_in[4], (const float*)d_in[6], (const float*)d_in[8],
      e1q, qmax, red0p, red1, outP, outQ);
}

// Round 11
// 69.497 us; speedup vs baseline: 9.2965x; 1.9659x over previous
//
#include <hip/hip_runtime.h>

typedef _Float16 f16;
typedef f16 f16x8 __attribute__((ext_vector_type(8)));
typedef f16 f16x4 __attribute__((ext_vector_type(4)));
typedef float f32x4 __attribute__((ext_vector_type(4)));
typedef float f32x2 __attribute__((ext_vector_type(2)));
typedef unsigned u32;

#define MFMA16(a, b, c) __builtin_amdgcn_mfma_f32_16x16x32_f16(a, b, c, 0, 0, 0)

// packed-weight offsets in f16 elements within d_ws (16x16x32 frag layout)
#define OFF_RW1A 0
#define OFF_RW2  10240
#define OFF_RW3  35840
#define OFF_QW1  46080
#define OFF_QW2  87040
#define OFF_QW3  112640
#define OFF_PW1  122880
#define OFF_PW2  163840
#define OFF_PW3  189440
#define PACK_BYTES 399360   // 199680 f16

// prep grid: [0,256) red0 partials | [256,355) pack | [355,363) qmax
//            [363,371) e1q | [371,627) c1/d1 | [627,1651) red1
#define PREP_BLOCKS 1651

struct InPtrs { const float* p[21]; };

__device__ const int g_mSrc[9] = {15, 17, 19, 9, 11, 13, 3, 5, 7};
__device__ const int g_mK0[9]  = {0, 0, 0, 128, 0, 0, 0, 0, 0};
__device__ const int g_mK[9]   = {64, 132, 132, 256, 132, 132, 256, 132, 132};
__device__ const int g_mN[9]   = {132, 132, 64, 132, 132, 64, 132, 132, 64};
__device__ const int g_mNT[9]  = {10, 10, 4, 10, 10, 4, 10, 10, 4};
__device__ const int g_mDst[9] = {OFF_RW1A, OFF_RW2, OFF_RW3, OFF_QW1, OFF_QW2, OFF_QW3,
                                  OFF_PW1, OFF_PW2, OFF_PW3};
__device__ const int g_mBlk0[9] = {256, 261, 274, 279, 299, 312, 317, 337, 350};

__global__ __launch_bounds__(256) void prep_kernel(InPtrs in, f16* __restrict__ wpk,
    float* __restrict__ c1, float* __restrict__ d1, float* __restrict__ e1q,
    float* __restrict__ qmax, float* __restrict__ red0p, float* __restrict__ red1)
{
  __shared__ float sbuf[1024];
  const int mb = blockIdx.x, t = threadIdx.x;

  if (mb < 256) {
    // red0 partial: max over 64 i's; block = (b, j-oct, i-half). Contiguous 2KB/i.
    const int b = mb >> 5, jo = (mb >> 1) & 15, ih = mb & 1;
    const float* base = in.p[2] + (size_t)b * 1048576 + (size_t)ih * 64 * 8192
                        + (size_t)jo * 512 + t * 2;
    f32x2 m[8];
    #pragma unroll
    for (int u = 0; u < 8; ++u) { m[u][0] = -3.4e38f; m[u][1] = -3.4e38f; }
    for (int i = 0; i < 64; i += 8) {
      #pragma unroll
      for (int u = 0; u < 8; ++u) {
        f32x2 v = *(const f32x2*)(base + (size_t)(i + u) * 8192);
        m[u][0] = fmaxf(m[u][0], v[0]);
        m[u][1] = fmaxf(m[u][1], v[1]);
      }
    }
    #pragma unroll
    for (int s = 4; s > 0; s >>= 1)
      #pragma unroll
      for (int u = 0; u < 4; ++u)
        if (u < s) {
          m[u][0] = fmaxf(m[u][0], m[u + s][0]);
          m[u][1] = fmaxf(m[u][1], m[u + s][1]);
        }
    *(f32x2*)(red0p + (size_t)ih * 65536 +
              ((size_t)(b * 128 + jo * 8 + (t >> 5))) * 64 + ((t * 2) & 63)) = m[0];
  } else if (mb < 355) {
    // weight pack into 16x16x32 MFMA fragment layout
    int mi = 8;
    while (mi > 0 && mb < g_mBlk0[mi]) --mi;
    const int NT = g_mNT[mi], K = g_mK[mi], N = g_mN[mi], K0 = g_mK0[mi];
    const int L = (mb - g_mBlk0[mi]) * 256 + t;
    const int lanes = ((K + 31) >> 5) * NT * 64;
    if (L < lanes) {
      const int lane = L & 63, tile = L >> 6;
      const int kk = tile / NT, nn = tile % NT;
      const float* src = in.p[g_mSrc[mi]];
      const int n = nn * 16 + (lane & 15);
      const int kb = kk * 32 + ((lane >> 4) << 3);
      f16x8 v;
      #pragma unroll
      for (int u = 0; u < 8; ++u) {
        const int k = kb + u;
        float f = (k < K && n < N) ? src[(size_t)(K0 + k) * N + n] : 0.f;
        v[u] = (f16)f;
      }
      *(f16x8*)(wpk + g_mDst[mi] + (size_t)L * 8) = v;
    }
  } else if (mb < 363) {
    // qmax[b,d] = max_i Q[b,i,d]
    const int b = mb - 355;
    const float* Qb = in.p[1] + (size_t)b * 128 * 128;
    const int d = t & 127, g = t >> 7;
    float m0 = -3.4e38f, m1 = m0, m2 = m0, m3 = m0;
    #pragma unroll
    for (int v = 0; v < 16; ++v) {
      const int i = g * 64 + v * 4;
      m0 = fmaxf(m0, Qb[(size_t)(i + 0) * 128 + d]);
      m1 = fmaxf(m1, Qb[(size_t)(i + 1) * 128 + d]);
      m2 = fmaxf(m2, Qb[(size_t)(i + 2) * 128 + d]);
      m3 = fmaxf(m3, Qb[(size_t)(i + 3) * 128 + d]);
    }
    sbuf[g * 128 + d] = fmaxf(fmaxf(m0, m1), fmaxf(m2, m3));
    __syncthreads();
    if (t < 128) qmax[b * 128 + t] = fmaxf(sbuf[t], sbuf[128 + t]);
  } else if (mb < 371) {
    // e1q[b,n] = P[b] . q_w1[0:128] + q_b1
    const int b = mb - 363;
    const float* P = in.p[0]; const float* qw1 = in.p[9]; const float* qb1 = in.p[10];
    if (t < 160) {
      float a = 0.f;
      if (t < 132) {
        float a0 = 0.f, a1 = 0.f, a2 = 0.f, a3 = 0.f;
        for (int k = 0; k < 128; k += 4) {
          a0 += P[b * 128 + k + 0] * qw1[(size_t)(k + 0) * 132 + t];
          a1 += P[b * 128 + k + 1] * qw1[(size_t)(k + 1) * 132 + t];
          a2 += P[b * 128 + k + 2] * qw1[(size_t)(k + 2) * 132 + t];
          a3 += P[b * 128 + k + 3] * qw1[(size_t)(k + 3) * 132 + t];
        }
        a = qb1[t] + (a0 + a1) + (a2 + a3);
      }
      e1q[b * 160 + t] = a;
    }
  } else if (mb < 627) {
    // c1/d1 (r-branch folded Q contributions), 4 Q-rows per block
    const int blk = mb - 371;
    const float* Q = in.p[1]; const float* rw1 = in.p[15]; const float* rb1 = in.p[16];
    for (int o = t; o < 512; o += 256) sbuf[o] = Q[(size_t)blk * 512 + o];
    __syncthreads();
    if (t < 160) {
      float cc[4], dd[4];
      #pragma unroll
      for (int r = 0; r < 4; ++r) { cc[r] = 0.f; dd[r] = 0.f; }
      if (t < 132) {
        const float bb = rb1[t];
        #pragma unroll
        for (int r = 0; r < 4; ++r) cc[r] = bb;
        for (int k = 0; k < 128; ++k) {
          const float wc = rw1[(size_t)(192 + k) * 132 + t];
          const float wd = rw1[(size_t)(64 + k) * 132 + t];
          #pragma unroll
          for (int r = 0; r < 4; ++r) {
            cc[r] += sbuf[r * 128 + k] * wc;
            dd[r] += sbuf[r * 128 + k] * wd;
          }
        }
      }
      for (int r = 0; r < 4; ++r) {
        c1[(size_t)(blk * 4 + r) * 160 + t] = cc[r];
        d1[(size_t)(blk * 4 + r) * 160 + t] = dd[r];
      }
    }
  } else {
    // red1[b,i,d] = max_j R[b,i,j,d]; one block per (b,i); contiguous loads.
    const int bi = mb - 627;
    const int d2 = t & 31, jg = t >> 5;
    const float* base = in.p[2] + (size_t)bi * 8192 + (size_t)jg * 1024 + d2 * 2;
    f32x2 m[4];
    #pragma unroll
    for (int u = 0; u < 4; ++u) { m[u][0] = -3.4e38f; m[u][1] = -3.4e38f; }
    #pragma unroll
    for (int v = 0; v < 16; v += 4) {
      #pragma unroll
      for (int u = 0; u < 4; ++u) {
        f32x2 vv = *(const f32x2*)(base + (size_t)(v + u) * 64);
        m[u][0] = fmaxf(m[u][0], vv[0]);
        m[u][1] = fmaxf(m[u][1], vv[1]);
      }
    }
    m[0][0] = fmaxf(fmaxf(m[0][0], m[1][0]), fmaxf(m[2][0], m[3][0]));
    m[0][1] = fmaxf(fmaxf(m[0][1], m[1][1]), fmaxf(m[2][1], m[3][1]));
    sbuf[jg * 64 + d2 * 2] = m[0][0];
    sbuf[jg * 64 + d2 * 2 + 1] = m[0][1];
    __syncthreads();
    if (t < 64) {
      float mm = sbuf[t];
      #pragma unroll
      for (int g2 = 1; g2 < 8; ++g2) mm = fmaxf(mm, sbuf[g2 * 64 + t]);
      red1[(size_t)bi * 64 + t] = mm;
    }
  }
}

__device__ __forceinline__ float sig5(float x) {
  return 1.f / (1.f + __expf(-5.f * x));
}

__device__ __forceinline__ u32 pk2(float a, float b) {
  typedef __fp16 fp16x2 __attribute__((ext_vector_type(2)));
  union { fp16x2 h; u32 u; } cv;
  cv.h = __builtin_amdgcn_cvt_pkrtz(a, b);
  return cv.u;
}

__device__ __forceinline__ f16x8 ld8(const float* p) {
  f32x4 v0 = *(const f32x4*)p, v1 = *(const f32x4*)(p + 4);
  union { u32 w[4]; f16x8 v; } U;
  U.w[0] = pk2(v0[0], v0[1]); U.w[1] = pk2(v0[2], v0[3]);
  U.w[2] = pk2(v1[0], v1[1]); U.w[3] = pk2(v1[2], v1[3]);
  return U.v;
}

__device__ __forceinline__ f16x8 ld8max(const float* p, int stride) {
  f32x4 a0 = *(const f32x4*)p, a1 = *(const f32x4*)(p + 4);
  f32x4 b0 = *(const f32x4*)(p + stride), b1 = *(const f32x4*)(p + stride + 4);
  union { u32 w[4]; f16x8 v; } U;
  U.w[0] = pk2(fmaxf(a0[0], b0[0]), fmaxf(a0[1], b0[1]));
  U.w[1] = pk2(fmaxf(a0[2], b0[2]), fmaxf(a0[3], b0[3]));
  U.w[2] = pk2(fmaxf(a1[0], b1[0]), fmaxf(a1[1], b1[1]));
  U.w[3] = pk2(fmaxf(a1[2], b1[2]), fmaxf(a1[3], b1[3]));
  return U.v;
}

// ---------------------------------------------------------------------------
// fused kernel: round-5-proven structure, doubled occupancy.
// 1033 blocks x 512 threads (8 waves: wm=w>>1 rows, wn=w&1 cols).
// LDS = Hs[128][168] f16 = 43KB -> 3 blocks/CU. Swapped-operand MFMA
// (D row = n, col = j); weights streamed from L2 (56-VGPR body).
// Blocks [0,8): Q (one per batch, 128 rows); block 8: P; [9,1033): R per (b,i).
// ---------------------------------------------------------------------------
__global__ __launch_bounds__(512, 4) void fused_kernel(
    const float* __restrict__ R, const float* __restrict__ c1, const float* __restrict__ d1,
    const float* __restrict__ rb2, const float* __restrict__ rb3,
    const f16* __restrict__ wpk, float* __restrict__ outR,
    const float* __restrict__ P, const float* __restrict__ Q,
    const float* __restrict__ qb2, const float* __restrict__ qb3,
    const float* __restrict__ pb1, const float* __restrict__ pb2, const float* __restrict__ pb3,
    const float* __restrict__ e1q, const float* __restrict__ qmax,
    const float* __restrict__ red0p, const float* __restrict__ red1,
    float* __restrict__ outP, float* __restrict__ outQ)
{
  __shared__ f16 Hs[128][168];       // 43008 B
  const int t = threadIdx.x, lane = t & 63, w = t >> 6;
  const int wm = w >> 1, wn = w & 1;
  const int lr = (lane >> 4) << 2;   // n-quad within 16-tile (D rows)
  const int lc = lane & 15;          // j within 16-tile (D cols / X row)
  const int lk = (lane >> 4) << 3;   // k offset within frag (in elements)
  const int rbase = wm * 32, nbase = wn * 80;
  const int blk = blockIdx.x;

  f32x4 acc[2][5];
  const f16x8 *W2p, *W3p;
  const float *b2p, *b3p;
  float* obase;
  int rowlim;

  if (blk >= 9) {
    // ================= R branch L1 (K=64) =================
    const int bi = blk - 9;
    const int b = bi >> 7;
    const float* c1r = c1 + (size_t)bi * 160;
    const float* d1b = d1 + (size_t)b * 128 * 160;
    f32x4 cvv[5];
    #pragma unroll
    for (int n5 = 0; n5 < 5; ++n5)
      cvv[n5] = *(const f32x4*)(c1r + nbase + n5 * 16 + lr);
    #pragma unroll
    for (int mi2 = 0; mi2 < 2; ++mi2) {
      const int jl = rbase + mi2 * 16 + lc;
      const float* dr = d1b + (size_t)jl * 160 + nbase + lr;
      #pragma unroll
      for (int n5 = 0; n5 < 5; ++n5)
        acc[mi2][n5] = cvv[n5] + *(const f32x4*)(dr + n5 * 16);
    }
    const f16x8* W1p = (const f16x8*)(wpk + OFF_RW1A);
    const float* Rb = R + (size_t)bi * 8192;
    #pragma unroll
    for (int c = 0; c < 2; ++c) {
      const f16x8 a0 = ld8(Rb + (size_t)(rbase + lc) * 64 + c * 32 + lk);
      const f16x8 a1 = ld8(Rb + (size_t)(rbase + 16 + lc) * 64 + c * 32 + lk);
      #pragma unroll
      for (int n5 = 0; n5 < 5; ++n5) {
        const f16x8 bf = W1p[(size_t)(c * 10 + wn * 5 + n5) * 64 + lane];
        acc[0][n5] = MFMA16(bf, a0, acc[0][n5]);
        acc[1][n5] = MFMA16(bf, a1, acc[1][n5]);
      }
    }
    b2p = rb2; b3p = rb3;
    W2p = (const f16x8*)(wpk + OFF_RW2);
    W3p = (const f16x8*)(wpk + OFF_RW3);
    obase = outR + (size_t)bi * 8192;
    rowlim = 128;
  } else {
    // ================= Q / P branch L1 (K=256) =================
    const bool isP = (blk == 8);
    const int b = blk;
    #pragma unroll
    for (int n5 = 0; n5 < 5; ++n5) {
      const int nb = nbase + n5 * 16 + lr;
      f32x4 cv = {0.f, 0.f, 0.f, 0.f};
      if (isP) { if (nb < 132) cv = *(const f32x4*)(pb1 + nb); }
      else cv = *(const f32x4*)(e1q + b * 160 + nb);
      acc[0][n5] = cv; acc[1][n5] = cv;
    }
    const f16x8* W1p = (const f16x8*)(wpk + (isP ? OFF_PW1 : OFF_QW1));
    #pragma unroll
    for (int c = 0; c < 8; ++c) {
      f16x8 x[2];
      #pragma unroll
      for (int mi2 = 0; mi2 < 2; ++mi2) {
        const int jl = rbase + mi2 * 16 + lc;
        if (isP) {
          const int rr = jl & 7;
          const float* s = (c < 4) ? (qmax + rr * 128 + c * 32 + lk)
                                   : (P + rr * 128 + (c - 4) * 32 + lk);
          x[mi2] = ld8(s);
        } else {
          const size_t row = (size_t)(b * 128 + jl);
          if (c < 4)      x[mi2] = ld8(Q + row * 128 + c * 32 + lk);
          else if (c < 6) x[mi2] = ld8max(red0p + row * 64 + (c - 4) * 32 + lk, 65536);
          else            x[mi2] = ld8(red1 + row * 64 + (c - 6) * 32 + lk);
        }
      }
      #pragma unroll
      for (int n5 = 0; n5 < 5; ++n5) {
        const f16x8 bf = W1p[(size_t)(c * 10 + wn * 5 + n5) * 64 + lane];
        acc[0][n5] = MFMA16(bf, x[0], acc[0][n5]);
        acc[1][n5] = MFMA16(bf, x[1], acc[1][n5]);
      }
    }
    b2p = isP ? pb2 : qb2; b3p = isP ? pb3 : qb3;
    W2p = (const f16x8*)(wpk + (isP ? OFF_PW2 : OFF_QW2));
    W3p = (const f16x8*)(wpk + (isP ? OFF_PW3 : OFF_QW3));
    obase = isP ? outP : (outQ + (size_t)b * 128 * 64);
    rowlim = isP ? 8 : 128;
  }

  // ---- shared tail: H1 store, L2, H2 store, L3, epilogue ----
  #pragma unroll
  for (int mi2 = 0; mi2 < 2; ++mi2) {
    const int jl = rbase + mi2 * 16 + lc;
    #pragma unroll
    for (int n5 = 0; n5 < 5; ++n5) {
      f16x4 hv;
      #pragma unroll
      for (int r = 0; r < 4; ++r) hv[r] = (f16)fmaxf(acc[mi2][n5][r], 0.f);
      *(f16x4*)(&Hs[jl][nbase + n5 * 16 + lr]) = hv;
    }
  }
  __syncthreads();

  // L2 (K=160)
  #pragma unroll
  for (int n5 = 0; n5 < 5; ++n5) {
    const int nb = nbase + n5 * 16 + lr;
    f32x4 bv = {0.f, 0.f, 0.f, 0.f};
    if (nb < 132) bv = *(const f32x4*)(b2p + nb);
    acc[0][n5] = bv; acc[1][n5] = bv;
  }
  #pragma unroll
  for (int kk = 0; kk < 5; ++kk) {
    const f16x8 a0 = *(const f16x8*)(&Hs[rbase + lc][kk * 32 + lk]);
    const f16x8 a1 = *(const f16x8*)(&Hs[rbase + 16 + lc][kk * 32 + lk]);
    #pragma unroll
    for (int n5 = 0; n5 < 5; ++n5) {
      const f16x8 bf = W2p[(size_t)(kk * 10 + wn * 5 + n5) * 64 + lane];
      acc[0][n5] = MFMA16(bf, a0, acc[0][n5]);
      acc[1][n5] = MFMA16(bf, a1, acc[1][n5]);
    }
  }
  __syncthreads();
  #pragma unroll
  for (int mi2 = 0; mi2 < 2; ++mi2) {
    const int jl = rbase + mi2 * 16 + lc;
    #pragma unroll
    for (int n5 = 0; n5 < 5; ++n5) {
      f16x4 hv;
      #pragma unroll
      for (int r = 0; r < 4; ++r) hv[r] = (f16)fmaxf(acc[mi2][n5][r], 0.f);
      *(f16x4*)(&Hs[jl][nbase + n5 * 16 + lr]) = hv;
    }
  }
  __syncthreads();

  // L3 (K=160, 64 out)
  f32x4 acc3[2][2];
  const int n3base = wn * 32;
  #pragma unroll
  for (int n2 = 0; n2 < 2; ++n2) {
    const f32x4 bv = *(const f32x4*)(b3p + n3base + n2 * 16 + lr);
    acc3[0][n2] = bv; acc3[1][n2] = bv;
  }
  #pragma unroll
  for (int kk = 0; kk < 5; ++kk) {
    const f16x8 a0 = *(const f16x8*)(&Hs[rbase + lc][kk * 32 + lk]);
    const f16x8 a1 = *(const f16x8*)(&Hs[rbase + 16 + lc][kk * 32 + lk]);
    #pragma unroll
    for (int n2 = 0; n2 < 2; ++n2) {
      const f16x8 bf = W3p[(size_t)(kk * 4 + wn * 2 + n2) * 64 + lane];
      acc3[0][n2] = MFMA16(bf, a0, acc3[0][n2]);
      acc3[1][n2] = MFMA16(bf, a1, acc3[1][n2]);
    }
  }
  #pragma unroll
  for (int mi2 = 0; mi2 < 2; ++mi2) {
    const int jl = rbase + mi2 * 16 + lc;
    if (jl < rowlim) {
      #pragma unroll
      for (int n2 = 0; n2 < 2; ++n2) {
        f32x4 ov;
        #pragma unroll
        for (int r = 0; r < 4; ++r) ov[r] = sig5(acc3[mi2][n2][r]);
        *(f32x4*)(obase + (size_t)jl * 64 + n3base + n2 * 16 + lr) = ov;
      }
    }
  }
}

extern "C" void kernel_launch(void* const* d_in, const int* in_sizes, int n_in,
                              void* d_out, int out_size, void* d_ws, size_t ws_size,
                              hipStream_t stream) {
  (void)in_sizes; (void)n_in; (void)out_size; (void)ws_size;
  InPtrs ip;
  for (int i = 0; i < 21; ++i) ip.p[i] = (const float*)d_in[i];

  char* ws = (char*)d_ws;
  f16* wpk = (f16*)ws;
  float* wsf = (float*)(ws + PACK_BYTES);
  float* c1 = wsf;
  float* d1 = wsf + 163840;
  float* e1q = wsf + 327680;
  float* qmax = wsf + 328960;
  float* red0p = wsf + 329984;   // 2 x 65536 partials
  float* red1 = wsf + 461056;

  float* outP = (float*)d_out;
  float* outQ = outP + 512;
  float* outR = outP + 66048;

  prep_kernel<<<dim3(PREP_BLOCKS), dim3(256), 0, stream>>>(ip, wpk, c1, d1, e1q, qmax,
                                                           red0p, red1);
  fused_kernel<<<dim3(1033), dim3(512), 0, stream>>>((const float*)d_in[2], c1, d1,
      (const float*)d_in[18], (const float*)d_in[20], wpk, outR,
      (const float*)d_in[0], (const float*)d_in[1],
      (const float*)d_in[12], (const float*)d_in[14],
      (const float*)d_in[4], (const float*)d_in[6], (const float*)d_in[8],
      e1q, qmax, red0p, red1, outP, outQ);
}